// Round 3
// baseline (53.662 us; speedup 1.0000x reference)
//
#include <hip/hip_runtime.h>
#include <cstdint>

#define DIM 64
#define NREL 8
#define BIN_CAP 16384                       // per-relation bin capacity (mean 8192)
#define CHUNKS_PER_BIN (BIN_CAP / 64)       // 256 waves per bin, 64 items/wave

// ---------------------------------------------------------------------------
// Kernel 1: scatter items into per-relation bins (unchanged from round 2).
// ---------------------------------------------------------------------------
__global__ __launch_bounds__(256) void scatter_kernel(
    const int* __restrict__ rel_idx,
    int* __restrict__ cnt,          // [NREL]
    int* __restrict__ sorted,       // [NREL * BIN_CAP]
    int B)
{
    __shared__ int wcnt[4][NREL];
    int tid  = threadIdx.x;
    int lane = tid & 63;
    int wv   = tid >> 6;
    int i = blockIdx.x * blockDim.x + tid;
    int r = (i < B) ? rel_idx[i] : -1;

    unsigned long long mymask = 0;
#pragma unroll
    for (int rr = 0; rr < NREL; ++rr) {
        unsigned long long mk = __ballot(r == rr);
        if (lane == 0) wcnt[wv][rr] = (int)__popcll(mk);
        if (rr == r) mymask = mk;
    }
    __syncthreads();

    if (tid < NREL) {
        int total = 0;
        int w0 = total; total += wcnt[0][tid];
        int w1 = total; total += wcnt[1][tid];
        int w2 = total; total += wcnt[2][tid];
        int w3 = total; total += wcnt[3][tid];
        int base = atomicAdd(&cnt[tid], total);
        wcnt[0][tid] = base + w0;
        wcnt[1][tid] = base + w1;
        wcnt[2][tid] = base + w2;
        wcnt[3][tid] = base + w3;
    }
    __syncthreads();

    if (i < B) {
        int rank = (int)__popcll(mymask & ((1ull << lane) - 1ull));
        int pos = wcnt[wv][r] + rank;
        if (pos < BIN_CAP)
            sorted[r * BIN_CAP + pos] = i;
    }
}

// ---------------------------------------------------------------------------
// Kernel 2: scoring, ONE LANE PER ITEM. Wave = 64 same-relation items.
// R[d][e] is wave-uniform -> SGPR broadcast operand (contiguous s_load_dwordx16,
// 1KB per d4 iteration). Per lane: gather own m-row/n-row (float4), 64x64
// FMAs into t[64] (static-indexed, stays in VGPRs), dot with n, sigmoid,
// scatter-store. No cross-lane ops, no per-item serialization.
// ---------------------------------------------------------------------------
__global__ __launch_bounds__(256) void score_kernel(
    const int* __restrict__ node_idx,
    const int* __restrict__ nb_idx,
    const float* __restrict__ node_table,
    const float* __restrict__ rel_table,
    const int* __restrict__ cnt,      // [NREL]
    const int* __restrict__ sorted,   // [NREL * BIN_CAP]
    float* __restrict__ out)
{
    int tid  = threadIdx.x;
    int lane = tid & 63;
    int gw   = blockIdx.x * (256 >> 6) + (tid >> 6);      // global wave id
    gw = __builtin_amdgcn_readfirstlane(gw);              // wave-uniform -> SGPR
    int r     = gw >> 8;                                  // CHUNKS_PER_BIN == 256
    int chunk = gw & 255;

    int c = cnt[r];
    if (c > BIN_CAP) c = BIN_CAP;
    int start = chunk << 6;
    if (start >= c) return;                               // uniform early-exit
    int rem   = c - start;
    bool valid = lane < rem;

    // clamp invalid lanes to slot 0 (always written when start < c)
    int b  = sorted[r * BIN_CAP + start + (valid ? lane : 0)];
    int ni = node_idx[b];
    int mi = nb_idx[b];

    const float4* mp = (const float4*)(node_table + (size_t)ni * DIM);
    const float4* np = (const float4*)(node_table + (size_t)mi * DIM);
    const float*  R  = rel_table + ((size_t)r << 12);     // SGPR base

    float t[64];
#pragma unroll
    for (int e = 0; e < 64; ++e) t[e] = 0.f;

    // d-outer: per iteration, 4 m-values (one float4) x 64 e-columns.
    // R rows d..d+3 are 1KB contiguous -> s_load_dwordx16 batches.
    float4 mq = mp[0];
#pragma unroll 1
    for (int d4 = 0; d4 < 16; ++d4) {
        float4 mn = mp[(d4 + 1) & 15];                    // prefetch next (last reloads [0], unused)
        const float* Rr = R + (d4 << 8);
#pragma unroll
        for (int e = 0; e < 64; ++e) {
            float acc = t[e];
            acc = fmaf(mq.x, Rr[e],        acc);
            acc = fmaf(mq.y, Rr[64  + e],  acc);
            acc = fmaf(mq.z, Rr[128 + e],  acc);
            acc = fmaf(mq.w, Rr[192 + e],  acc);
            t[e] = acc;
        }
        mq = mn;
    }

    // score = sum_e t[e] * n[e]
    float s0 = 0.f, s1 = 0.f, s2 = 0.f, s3 = 0.f;
#pragma unroll
    for (int e4 = 0; e4 < 16; ++e4) {
        float4 n4 = np[e4];
        s0 = fmaf(t[4 * e4 + 0], n4.x, s0);
        s1 = fmaf(t[4 * e4 + 1], n4.y, s1);
        s2 = fmaf(t[4 * e4 + 2], n4.z, s2);
        s3 = fmaf(t[4 * e4 + 3], n4.w, s3);
    }
    float s = (s0 + s1) + (s2 + s3);

    if (valid)
        out[b] = 1.0f / (1.0f + __expf(-s));
}

extern "C" void kernel_launch(void* const* d_in, const int* in_sizes, int n_in,
                              void* d_out, int out_size, void* d_ws, size_t ws_size,
                              hipStream_t stream) {
    const int*   node_idx   = (const int*)d_in[0];
    const int*   rel_idx    = (const int*)d_in[1];
    const int*   nb_idx     = (const int*)d_in[2];
    const float* node_table = (const float*)d_in[3];
    const float* rel_table  = (const float*)d_in[4];
    float* out = (float*)d_out;
    int B = in_sizes[0];   // 65536

    // ws layout: [0,32): cnt[8]; [256,...): sorted[NREL*BIN_CAP] (512 KB)
    int* cnt    = (int*)d_ws;
    int* sorted = (int*)((char*)d_ws + 256);

    hipMemsetAsync(cnt, 0, NREL * sizeof(int), stream);

    int sblocks = (B + 255) / 256;
    scatter_kernel<<<sblocks, 256, 0, stream>>>(rel_idx, cnt, sorted, B);

    int waves   = NREL * CHUNKS_PER_BIN;      // 2048 waves
    int mblocks = (waves * 64) / 256;         // 512 blocks
    score_kernel<<<mblocks, 256, 0, stream>>>(node_idx, nb_idx, node_table,
                                              rel_table, cnt, sorted, out);
}